// Round 2
// baseline (583.290 us; speedup 1.0000x reference)
//
#include <hip/hip_runtime.h>

// WeightedLoss: loss_i = (target_i == 1) ? 1 - sigmoid(pred_i) : 0.1 ; out = mean(loss)
// 1 - sigmoid(x) = 1 / (1 + exp(x))
//
// R1 post-mortem: grid-stride loop with 2 loads in flight per wave was
// latency-bound (1.4 TB/s HBM, 18% VALU). R2: 4x unrolled fast path — 8
// independent dwordx4 loads issued before any compute (8 KB/wave in flight,
// ~60 VGPR -> still full occupancy), int32 indexing, exact-trip-count kernel.

#define BLOCK  256
#define UNROLL 4   // float4 groups per thread

__global__ __launch_bounds__(BLOCK)
void wloss_exact(const float4* __restrict__ p4,
                 const int4*   __restrict__ t4,
                 float* __restrict__ out, float inv_n) {
    const int base = blockIdx.x * (BLOCK * UNROLL) + threadIdx.x;

    // Issue all 8 loads back-to-back before any use.
    float4 p[UNROLL];
    int4   t[UNROLL];
#pragma unroll
    for (int u = 0; u < UNROLL; ++u) p[u] = p4[base + u * BLOCK];
#pragma unroll
    for (int u = 0; u < UNROLL; ++u) t[u] = t4[base + u * BLOCK];

    float acc = 0.0f;
#pragma unroll
    for (int u = 0; u < UNROLL; ++u) {
        float l0 = (t[u].x == 1) ? 1.0f / (1.0f + __expf(p[u].x)) : 0.1f;
        float l1 = (t[u].y == 1) ? 1.0f / (1.0f + __expf(p[u].y)) : 0.1f;
        float l2 = (t[u].z == 1) ? 1.0f / (1.0f + __expf(p[u].z)) : 0.1f;
        float l3 = (t[u].w == 1) ? 1.0f / (1.0f + __expf(p[u].w)) : 0.1f;
        acc += (l0 + l1) + (l2 + l3);
    }

    // Wave-64 shuffle reduction
#pragma unroll
    for (int off = 32; off > 0; off >>= 1)
        acc += __shfl_down(acc, off, 64);

    __shared__ float smem[BLOCK / 64];
    const int lane = threadIdx.x & 63;
    const int wave = threadIdx.x >> 6;
    if (lane == 0) smem[wave] = acc;
    __syncthreads();
    if (threadIdx.x == 0) {
        float bsum = (smem[0] + smem[1]) + (smem[2] + smem[3]);
        atomicAdd(out, bsum * inv_n);
    }
}

// Generic fallback for n not divisible by 4*BLOCK*UNROLL (correctness for any n).
__global__ __launch_bounds__(BLOCK)
void wloss_generic(const float* __restrict__ pred,
                   const int*   __restrict__ tgt,
                   float* __restrict__ out,
                   long long n, float inv_n) {
    const long long n4     = n >> 2;
    const long long tid    = (long long)blockIdx.x * blockDim.x + threadIdx.x;
    const long long stride = (long long)gridDim.x * blockDim.x;

    const float4* p4 = (const float4*)pred;
    const int4*   t4 = (const int4*)tgt;

    float acc = 0.0f;
    for (long long i = tid; i < n4; i += stride) {
        float4 p = p4[i];
        int4   t = t4[i];
        acc += (t.x == 1) ? 1.0f / (1.0f + __expf(p.x)) : 0.1f;
        acc += (t.y == 1) ? 1.0f / (1.0f + __expf(p.y)) : 0.1f;
        acc += (t.z == 1) ? 1.0f / (1.0f + __expf(p.z)) : 0.1f;
        acc += (t.w == 1) ? 1.0f / (1.0f + __expf(p.w)) : 0.1f;
    }
    if (blockIdx.x == 0) {
        for (long long i = (n4 << 2) + threadIdx.x; i < n; i += blockDim.x)
            acc += (tgt[i] == 1) ? 1.0f / (1.0f + __expf(pred[i])) : 0.1f;
    }

#pragma unroll
    for (int off = 32; off > 0; off >>= 1)
        acc += __shfl_down(acc, off, 64);

    __shared__ float smem[BLOCK / 64];
    const int lane = threadIdx.x & 63;
    const int wave = threadIdx.x >> 6;
    if (lane == 0) smem[wave] = acc;
    __syncthreads();
    if (threadIdx.x == 0) {
        float bsum = (smem[0] + smem[1]) + (smem[2] + smem[3]);
        atomicAdd(out, bsum * inv_n);
    }
}

extern "C" void kernel_launch(void* const* d_in, const int* in_sizes, int n_in,
                              void* d_out, int out_size, void* d_ws, size_t ws_size,
                              hipStream_t stream) {
    const float* pred = (const float*)d_in[0];
    const int*   tgt  = (const int*)d_in[1];
    float*       out  = (float*)d_out;

    const long long n = (long long)in_sizes[0];
    const float inv_n = 1.0f / (float)n;

    // Zero the accumulator (d_out is poisoned before every launch).
    hipMemsetAsync(out, 0, sizeof(float), stream);

    const long long per_block = 4LL * BLOCK * UNROLL;  // elements per block
    if (n % per_block == 0) {
        const int grid = (int)(n / per_block);  // 16384 for N=2^26
        wloss_exact<<<grid, BLOCK, 0, stream>>>((const float4*)pred,
                                                (const int4*)tgt, out, inv_n);
    } else {
        long long g = ((n >> 2) + BLOCK - 1) / BLOCK;
        if (g > 8192) g = 8192;
        if (g < 1)    g = 1;
        wloss_generic<<<(int)g, BLOCK, 0, stream>>>(pred, tgt, out, n, inv_n);
    }
}

// Round 3
// 506.495 us; speedup vs baseline: 1.1516x; 1.1516x over previous
//
#include <hip/hip_runtime.h>

// WeightedLoss: loss_i = (target_i == 1) ? 1 - sigmoid(pred_i) : 0.1 ; out = mean(loss)
// 1 - sigmoid(x) = 1 / (1 + exp(x))
//
// R2 post-mortem: source-level "load everything first" was re-serialized by the
// scheduler (VGPR_Count=20 proves only ~2 loads in flight). R3: software-pipelined
// grid-stride loop, prefetch depth 2 — loads for iteration k issue before compute
// of k-1, so the compiler's as-late-as-possible s_waitcnt lands after a full
// compute block instead of immediately after issue. Persistent grid: 2048 blocks
// (8/CU), 32 uniform iterations, no bounds checks in the hot loop.

#define BLOCK 256

__device__ __forceinline__ float loss4(float4 p, int4 t) {
    float l0 = (t.x == 1) ? 1.0f / (1.0f + __expf(p.x)) : 0.1f;
    float l1 = (t.y == 1) ? 1.0f / (1.0f + __expf(p.y)) : 0.1f;
    float l2 = (t.z == 1) ? 1.0f / (1.0f + __expf(p.z)) : 0.1f;
    float l3 = (t.w == 1) ? 1.0f / (1.0f + __expf(p.w)) : 0.1f;
    return (l0 + l1) + (l2 + l3);
}

__device__ __forceinline__ void block_reduce_atomic(float acc, float inv_n,
                                                    float* __restrict__ out) {
#pragma unroll
    for (int off = 32; off > 0; off >>= 1)
        acc += __shfl_down(acc, off, 64);
    __shared__ float smem[BLOCK / 64];
    const int lane = threadIdx.x & 63;
    const int wave = threadIdx.x >> 6;
    if (lane == 0) smem[wave] = acc;
    __syncthreads();
    if (threadIdx.x == 0) {
        float bsum = (smem[0] + smem[1]) + (smem[2] + smem[3]);
        atomicAdd(out, bsum * inv_n);
    }
}

// Fast path: n4 divisible by stride, iters >= 2. Software pipeline, depth 2.
__global__ __launch_bounds__(BLOCK)
void wloss_pipe(const float4* __restrict__ p4,
                const int4*   __restrict__ t4,
                float* __restrict__ out,
                int iters, int stride, float inv_n) {
    int i = blockIdx.x * BLOCK + threadIdx.x;

    // Prologue: fill two pipeline slots.
    float4 pA = p4[i];          int4 tA = t4[i];
    float4 pB = p4[i + stride]; int4 tB = t4[i + stride];
    int idx = i + 2 * stride;

    float acc = 0.0f;
    for (int k = 0; k < iters - 2; ++k) {
        // Issue next loads BEFORE computing on slot A — waitcnt for these
        // lands after the compute below.
        float4 pN = p4[idx];
        int4   tN = t4[idx];
        idx += stride;
        acc += loss4(pA, tA);
        // Rotate pipeline (compiler unrolls x2/x3 and renames, removing movs).
        pA = pB; tA = tB;
        pB = pN; tB = tN;
    }
    // Epilogue: drain both slots.
    acc += loss4(pA, tA);
    acc += loss4(pB, tB);

    block_reduce_atomic(acc, inv_n, out);
}

// Generic fallback for arbitrary n (R1 structure).
__global__ __launch_bounds__(BLOCK)
void wloss_generic(const float* __restrict__ pred,
                   const int*   __restrict__ tgt,
                   float* __restrict__ out,
                   long long n, float inv_n) {
    const long long n4     = n >> 2;
    const long long tid    = (long long)blockIdx.x * blockDim.x + threadIdx.x;
    const long long stride = (long long)gridDim.x * blockDim.x;

    const float4* p4 = (const float4*)pred;
    const int4*   t4 = (const int4*)tgt;

    float acc = 0.0f;
    for (long long i = tid; i < n4; i += stride)
        acc += loss4(p4[i], t4[i]);
    if (blockIdx.x == 0) {
        for (long long i = (n4 << 2) + threadIdx.x; i < n; i += blockDim.x)
            acc += (tgt[i] == 1) ? 1.0f / (1.0f + __expf(pred[i])) : 0.1f;
    }
    block_reduce_atomic(acc, inv_n, out);
}

extern "C" void kernel_launch(void* const* d_in, const int* in_sizes, int n_in,
                              void* d_out, int out_size, void* d_ws, size_t ws_size,
                              hipStream_t stream) {
    const float* pred = (const float*)d_in[0];
    const int*   tgt  = (const int*)d_in[1];
    float*       out  = (float*)d_out;

    const long long n = (long long)in_sizes[0];
    const float inv_n = 1.0f / (float)n;

    hipMemsetAsync(out, 0, sizeof(float), stream);

    const long long n4 = n >> 2;
    const int grid = 2048;                       // 8 blocks/CU on 256 CUs
    const long long stride = (long long)grid * BLOCK;  // 2^19 float4/thread-step

    if ((n & 3) == 0 && n4 % stride == 0 && n4 / stride >= 2) {
        const int iters = (int)(n4 / stride);    // 32 for N=2^26
        wloss_pipe<<<grid, BLOCK, 0, stream>>>((const float4*)pred,
                                               (const int4*)tgt, out,
                                               iters, (int)stride, inv_n);
    } else {
        long long g = (n4 + BLOCK - 1) / BLOCK;
        if (g > 8192) g = 8192;
        if (g < 1)    g = 1;
        wloss_generic<<<(int)g, BLOCK, 0, stream>>>(pred, tgt, out, n, inv_n);
    }
}

// Round 4
// 502.019 us; speedup vs baseline: 1.1619x; 1.0089x over previous
//
#include <hip/hip_runtime.h>

// WeightedLoss: loss_i = (target_i == 1) ? 1 - sigmoid(pred_i) : 0.1 ; out = mean(loss)
// 1 - sigmoid(x) = 1 / (1 + exp(x))
//
// R3 post-mortem: depth-2 pipeline got kernel to ~155us (3.5 TB/s effective).
// Per-SIMD wave-serialized iteration wall time (~700 cyc) is comparable to the
// ~900 cyc loaded HBM latency -> depth-2 coverage marginal. R4: widen each
// pipeline slot to 2x(float4+int4) = 4 KB/wave-slot, 8 loads in steady flight;
// waitcnt for slot k lands ~2 compute blocks (~2800 cyc) after issue.
// ~56 VGPR -> still 8 waves/SIMD.

#define BLOCK 256

__device__ __forceinline__ float loss4(float4 p, int4 t) {
    float l0 = (t.x == 1) ? 1.0f / (1.0f + __expf(p.x)) : 0.1f;
    float l1 = (t.y == 1) ? 1.0f / (1.0f + __expf(p.y)) : 0.1f;
    float l2 = (t.z == 1) ? 1.0f / (1.0f + __expf(p.z)) : 0.1f;
    float l3 = (t.w == 1) ? 1.0f / (1.0f + __expf(p.w)) : 0.1f;
    return (l0 + l1) + (l2 + l3);
}

__device__ __forceinline__ void block_reduce_atomic(float acc, float inv_n,
                                                    float* __restrict__ out) {
#pragma unroll
    for (int off = 32; off > 0; off >>= 1)
        acc += __shfl_down(acc, off, 64);
    __shared__ float smem[BLOCK / 64];
    const int lane = threadIdx.x & 63;
    const int wave = threadIdx.x >> 6;
    if (lane == 0) smem[wave] = acc;
    __syncthreads();
    if (threadIdx.x == 0) {
        float bsum = (smem[0] + smem[1]) + (smem[2] + smem[3]);
        atomicAdd(out, bsum * inv_n);
    }
}

// Fast path: pipeline depth 2, each slot = 2 float4 + 2 int4 (4 KB/wave-slot).
// stride is in float4 units; block b covers [b*2*BLOCK, b*2*BLOCK + 2*BLOCK).
__global__ __launch_bounds__(BLOCK)
void wloss_pipe2(const float4* __restrict__ p4,
                 const int4*   __restrict__ t4,
                 float* __restrict__ out,
                 int iters, int stride, float inv_n) {
    const int i = blockIdx.x * (2 * BLOCK) + threadIdx.x;
    const int j = i + BLOCK;

    // Prologue: fill both pipeline slots (8 dwordx4 loads in flight).
    float4 pA0 = p4[i];          float4 pA1 = p4[j];
    int4   tA0 = t4[i];          int4   tA1 = t4[j];
    float4 pB0 = p4[i + stride]; float4 pB1 = p4[j + stride];
    int4   tB0 = t4[i + stride]; int4   tB1 = t4[j + stride];
    int idx = i + 2 * stride;
    int jdx = j + 2 * stride;

    float acc = 0.0f;
    for (int k = 0; k < iters - 2; ++k) {
        // Next slot's 4 loads issue before slot A's compute.
        float4 pN0 = p4[idx]; float4 pN1 = p4[jdx];
        int4   tN0 = t4[idx]; int4   tN1 = t4[jdx];
        idx += stride; jdx += stride;

        acc += loss4(pA0, tA0) + loss4(pA1, tA1);

        pA0 = pB0; pA1 = pB1; tA0 = tB0; tA1 = tB1;
        pB0 = pN0; pB1 = pN1; tB0 = tN0; tB1 = tN1;
    }
    // Drain.
    acc += loss4(pA0, tA0) + loss4(pA1, tA1);
    acc += loss4(pB0, tB0) + loss4(pB1, tB1);

    block_reduce_atomic(acc, inv_n, out);
}

// Generic fallback for arbitrary n.
__global__ __launch_bounds__(BLOCK)
void wloss_generic(const float* __restrict__ pred,
                   const int*   __restrict__ tgt,
                   float* __restrict__ out,
                   long long n, float inv_n) {
    const long long n4     = n >> 2;
    const long long tid    = (long long)blockIdx.x * blockDim.x + threadIdx.x;
    const long long stride = (long long)gridDim.x * blockDim.x;

    const float4* p4 = (const float4*)pred;
    const int4*   t4 = (const int4*)tgt;

    float acc = 0.0f;
    for (long long i = tid; i < n4; i += stride)
        acc += loss4(p4[i], t4[i]);
    if (blockIdx.x == 0) {
        for (long long i = (n4 << 2) + threadIdx.x; i < n; i += blockDim.x)
            acc += (tgt[i] == 1) ? 1.0f / (1.0f + __expf(pred[i])) : 0.1f;
    }
    block_reduce_atomic(acc, inv_n, out);
}

extern "C" void kernel_launch(void* const* d_in, const int* in_sizes, int n_in,
                              void* d_out, int out_size, void* d_ws, size_t ws_size,
                              hipStream_t stream) {
    const float* pred = (const float*)d_in[0];
    const int*   tgt  = (const int*)d_in[1];
    float*       out  = (float*)d_out;

    const long long n = (long long)in_sizes[0];
    const float inv_n = 1.0f / (float)n;

    hipMemsetAsync(out, 0, sizeof(float), stream);

    const long long n4 = n >> 2;
    const int grid = 2048;                              // 8 blocks/CU
    const long long stride = (long long)grid * (2 * BLOCK); // float4 units/iter

    if ((n & 3) == 0 && n4 % stride == 0 && n4 / stride >= 2) {
        const int iters = (int)(n4 / stride);           // 16 for N=2^26
        wloss_pipe2<<<grid, BLOCK, 0, stream>>>((const float4*)pred,
                                                (const int4*)tgt, out,
                                                iters, (int)stride, inv_n);
    } else {
        long long g = (n4 + BLOCK - 1) / BLOCK;
        if (g > 8192) g = 8192;
        if (g < 1)    g = 1;
        wloss_generic<<<(int)g, BLOCK, 0, stream>>>(pred, tgt, out, n, inv_n);
    }
}